// Round 11
// baseline (66.656 us; speedup 1.0000x reference)
//
#include <hip/hip_runtime.h>
#include <hip/hip_fp16.h>
#include <math.h>

#define NQ 8
#define DK 64
#define NB 8
#define NS 1024
#define RB 8            // rows per block in attn kernel
#define EPITCH 1032     // padded halfs per e16 row (breaks 1024-stride bank aliasing)

typedef _Float16 h2v __attribute__((ext_vector_type(2)));
typedef _Float16 h4v __attribute__((ext_vector_type(4)));
typedef float    f4v __attribute__((ext_vector_type(4)));

__device__ __forceinline__ float fdot2h(unsigned qu, unsigned ku, float acc) {
#if defined(__has_builtin) && __has_builtin(__builtin_amdgcn_fdot2)
    union { unsigned u; h2v h; } a, b;
    a.u = qu; b.u = ku;
    return __builtin_amdgcn_fdot2(a.h, b.h, acc, false);
#else
    __half2 qh = *(__half2*)&qu, kh = *(__half2*)&ku;
    float2 qf = __half22float2(qh), kf = __half22float2(kh);
    return fmaf(qf.x, kf.x, fmaf(qf.y, kf.y, acc));
#endif
}

// ---------------- prep: Vt fp16 GEMM (blocks 0..2047) + density features ----------------
// qdh/kdh fp16 [tok][n*4 + {d0,d1,re,im}]; factor 2 folded into kdh cross terms.
// Vt fp16 [b*64+d][t]  (transposed values for MFMA B-operand)
__global__ __launch_bounds__(256) void prep_kernel(
    const float* __restrict__ x,
    const float* __restrict__ theta_q,
    const float* __restrict__ theta_k,
    const float* __restrict__ Wv,
    const float* __restrict__ bv,
    __half* __restrict__ qdh, __half* __restrict__ kdh,
    __half* __restrict__ vt) {
    int bid = blockIdx.x;
    int tid = threadIdx.x;
    if (bid < 2048) {
        // values = x @ Wv^T + bv (4 partial chains), stored fp16 transposed
        int t = bid * 4 + (tid >> 6);
        int d = tid & 63;
        const float4* xr = (const float4*)(x + (size_t)t * DK);
        const float4* wr = (const float4*)(Wv + (size_t)d * DK);
        float a0 = bv[d], a1 = 0.f, a2 = 0.f, a3 = 0.f;
#pragma unroll
        for (int j = 0; j < DK / 4; ++j) {
            float4 xv = xr[j], wv = wr[j];
            a0 = fmaf(xv.x, wv.x, a0);
            a1 = fmaf(xv.y, wv.y, a1);
            a2 = fmaf(xv.z, wv.z, a2);
            a3 = fmaf(xv.w, wv.w, a3);
        }
        float v = (a0 + a1) + (a2 + a3);
        int b = t >> 10, ti = t & 1023;
        vt[(((size_t)(b * DK + d)) << 10) + ti] = __float2half_rn(v);
    } else {
        // per-(side,qubit) theta trig table, computed once per block
        __shared__ float tt[2][NQ][6];   // ct,st,cmpo,smpo,cpmo,spmo
        if (tid < 16) {
            int side = tid >> 3, n = tid & 7;
            const float* thp = side ? theta_k : theta_q;
            float phi = thp[n * 3 + 0], th = thp[n * 3 + 1], om = thp[n * 3 + 2];
            float st, ct; __sincosf(0.5f * th, &st, &ct);
            float smpo, cmpo; __sincosf(0.5f * (phi + om), &smpo, &cmpo);
            float spmo, cpmo; __sincosf(0.5f * (phi - om), &spmo, &cpmo);
            tt[side][n][0] = ct;  tt[side][n][1] = st;
            tt[side][n][2] = cmpo; tt[side][n][3] = smpo;
            tt[side][n][4] = cpmo; tt[side][n][5] = spmo;
        }
        __syncthreads();

        int gid = (bid - 2048) * 256 + tid;   // 0..65535
        int tok = gid >> 3;
        int n = gid & 7;
        float xin = x[(size_t)tok * DK + n];
        float ex = __expf(2.0f * xin);               // fast tanh
        float xn = 1.0f - 2.0f / (ex + 1.0f);
        float s, c;
        __sincosf(xn * 1.57079632679489662f, &s, &c);

#pragma unroll
        for (int side = 0; side < 2; ++side) {
            float ct = tt[side][n][0], st = tt[side][n][1];
            float cmpo = tt[side][n][2], smpo = tt[side][n][3];
            float cpmo = tt[side][n][4], spmo = tt[side][n][5];
            float a = ct * c, b2 = st * s, cc = st * c, d2 = ct * s;
            float a0re =  cmpo * a - cpmo * b2;
            float a0im = -smpo * a - spmo * b2;
            float a1re =  cpmo * cc + cmpo * d2;
            float a1im = -spmo * cc + smpo * d2;
            float d0 = fmaf(a0re, a0re, a0im * a0im);
            float d1 = fmaf(a1re, a1re, a1im * a1im);
            float ur = fmaf(a1re, a0re, a1im * a0im);
            float ui = fmaf(a1im, a0re, -a1re * a0im);
            if (side == 0) {
                __half2* qp = (__half2*)(qdh + (size_t)tok * 32 + n * 4);
                qp[0] = __floats2half2_rn(d0, d1);
                qp[1] = __floats2half2_rn(ur, ui);
            } else {
                __half2* kp = (__half2*)(kdh + (size_t)tok * 32 + n * 4);
                kp[0] = __floats2half2_rn(d0, d1);
                kp[1] = __floats2half2_rn(2.f * ur, 2.f * ui);
            }
        }
    }
}

// ---------------- attn: fused scores -> softmax -> attn + MFMA PV ----------------
// 1024 blocks x 256 threads (4 waves); block owns 8 rows of one batch.
// Phase 1: wave w owns token slice [256w, 256w+256) in VGPRs, all 8 rows (R10-proven).
// Phase 3: out[8x64] = e16[8x1024] @ V[1024x64] via v_mfma_f32_16x16x16_f16.
__global__ __launch_bounds__(256, 4) void attn_kernel(
    const __half* __restrict__ qdh, const __half* __restrict__ kdh,
    const __half* __restrict__ vt,
    float* __restrict__ out, float* __restrict__ attn) {
    __shared__ __align__(16) __half e16[RB][EPITCH];   // 16.5 KB
    __shared__ float red_lds[4][RB];
    __shared__ float inv_lds[RB];

    int tid = threadIdx.x;
    int gr0 = blockIdx.x * RB;            // global row base (= b*NS + s0)
    int b = gr0 >> 10;
    int w = tid >> 6, lane = tid & 63;

    const __half* kfb = kdh + (size_t)b * NS * 32;

    // ---- Phase 1: load wave's K slice (4 tokens per lane, 64 VGPRs) ----
    int t0 = w * 256;
    uint4 kv[4][4];
#pragma unroll
    for (int j = 0; j < 4; ++j) {
        const uint4* kp = (const uint4*)(kfb + (size_t)(t0 + j * 64 + lane) * 32);
        kv[j][0] = kp[0]; kv[j][1] = kp[1]; kv[j][2] = kp[2]; kv[j][3] = kp[3];
    }

    float sums[RB];
#pragma unroll
    for (int r = 0; r < RB; ++r) sums[r] = 0.f;

#pragma unroll
    for (int r = 0; r < RB; ++r) {
        const unsigned* qp = (const unsigned*)(qdh + (size_t)(gr0 + r) * 32);
        unsigned sq[16];
#pragma unroll
        for (int i = 0; i < 16; ++i) sq[i] = __builtin_amdgcn_readfirstlane(qp[i]);
#pragma unroll
        for (int j = 0; j < 4; ++j) {
            float m0 = fdot2h(sq[ 0], kv[j][0].x, fdot2h(sq[ 1], kv[j][0].y, 0.f));
            float m1 = fdot2h(sq[ 2], kv[j][0].z, fdot2h(sq[ 3], kv[j][0].w, 0.f));
            float m2 = fdot2h(sq[ 4], kv[j][1].x, fdot2h(sq[ 5], kv[j][1].y, 0.f));
            float m3 = fdot2h(sq[ 6], kv[j][1].z, fdot2h(sq[ 7], kv[j][1].w, 0.f));
            float m4 = fdot2h(sq[ 8], kv[j][2].x, fdot2h(sq[ 9], kv[j][2].y, 0.f));
            float m5 = fdot2h(sq[10], kv[j][2].z, fdot2h(sq[11], kv[j][2].w, 0.f));
            float m6 = fdot2h(sq[12], kv[j][3].x, fdot2h(sq[13], kv[j][3].y, 0.f));
            float m7 = fdot2h(sq[14], kv[j][3].z, fdot2h(sq[15], kv[j][3].w, 0.f));
            float core = ((m0 * m1) * (m2 * m3)) * ((m4 * m5) * (m6 * m7));
            float e = __expf(fmaf(core, 0.5f, 0.5f));   // score in [0.5,1] -> no max
            e16[r][t0 + j * 64 + lane] = __float2half_rn(e);
            sums[r] += e;
        }
    }

    // per-wave partial row sums -> cross-wave combine
#pragma unroll
    for (int r = 0; r < RB; ++r) {
#pragma unroll
        for (int m = 1; m < 64; m <<= 1) sums[r] += __shfl_xor(sums[r], m, 64);
    }
    if (lane == 0) {
#pragma unroll
        for (int r = 0; r < RB; ++r) red_lds[w][r] = sums[r];
    }
    __syncthreads();
    if (tid < RB)
        inv_lds[tid] = 1.f / (red_lds[0][tid] + red_lds[1][tid] + red_lds[2][tid] + red_lds[3][tid]);
    __syncthreads();

    // ---- Phase 2: write normalized attn (coalesced float4) ----
    float* ab = attn + (size_t)gr0 * NS;
#pragma unroll
    for (int r = 0; r < RB; ++r) {
        float iv = inv_lds[r];
        uint2 raw = *(const uint2*)&e16[r][tid * 4];
        __half2* hp = (__half2*)&raw;
        float2 lo = __half22float2(hp[0]), hi = __half22float2(hp[1]);
        *(float4*)&ab[(size_t)r * NS + tid * 4] =
            make_float4(lo.x * iv, lo.y * iv, hi.x * iv, hi.y * iv);
    }

    // ---- Phase 3: MFMA PV. wave w -> dims [w*16, w*16+16); A rows 8..15 unused ----
#if defined(__has_builtin) && __has_builtin(__builtin_amdgcn_mfma_f32_16x16x16f16)
    {
        int arow = lane & 15; if (arow >= RB) arow -= RB;   // rows 8-15 mirror 0-7 (junk rows never stored)
        int kofs = (lane >> 4) * 4;
        const __half* ap = &e16[arow][kofs];
        const __half* bp = vt + (((size_t)(b * DK + w * 16 + (lane & 15))) << 10) + kofs;
        f4v acc = {0.f, 0.f, 0.f, 0.f};
#pragma unroll 4
        for (int kt = 0; kt < 64; ++kt) {
            h4v a = *(const h4v*)(ap + kt * 16);
            h4v bb = *(const h4v*)(bp + kt * 16);
            acc = __builtin_amdgcn_mfma_f32_16x16x16f16(a, bb, acc, 0, 0, 0);
        }
        // C layout: col = lane&15, row = (lane>>4)*4 + reg; store rows 0..7
        if (lane < 32) {
            int ccol = lane & 15;
            int rbase = (lane >> 4) * 4;
#pragma unroll
            for (int reg = 0; reg < 4; ++reg) {
                int row = rbase + reg;
                out[((size_t)(gr0 + row)) * DK + w * 16 + ccol] = acc[reg] * inv_lds[row];
            }
        }
    }
#else
    // correctness fallback: scalar dot per output element
    {
        const __half* vtb = vt + (((size_t)b * DK) << 10);
        for (int idx = tid; idx < RB * DK; idx += 256) {
            int row = idx >> 6, d = idx & 63;
            const __half* ep = &e16[row][0];
            const __half* vp = vtb + ((size_t)d << 10);
            float o = 0.f;
            for (int t = 0; t < NS; ++t)
                o = fmaf(__half2float(ep[t]), __half2float(vp[t]), o);
            out[((size_t)(gr0 + row)) * DK + d] = o * inv_lds[row];
        }
    }
#endif
}

extern "C" void kernel_launch(void* const* d_in, const int* in_sizes, int n_in,
                              void* d_out, int out_size, void* d_ws, size_t ws_size,
                              hipStream_t stream) {
    const float* x       = (const float*)d_in[0];
    const float* theta_q = (const float*)d_in[1];
    const float* theta_k = (const float*)d_in[2];
    const float* W_v     = (const float*)d_in[3];
    const float* b_v     = (const float*)d_in[4];

    float* out  = (float*)d_out;                        // [8,1024,64]
    float* attn = (float*)d_out + (size_t)NB * NS * DK; // [8,1024,1024]

    __half* qdh = (__half*)d_ws;                         // 512 KB fp16
    __half* kdh = qdh + (size_t)NB * NS * 32;            // 512 KB fp16
    __half* vt  = kdh + (size_t)NB * NS * 32;            // 1 MB fp16 (transposed values)

    prep_kernel<<<2048 + NB * NS * NQ / 256, 256, 0, stream>>>(
        x, theta_q, theta_k, W_v, b_v, qdh, kdh, vt);
    attn_kernel<<<NB * NS / RB, 256, 0, stream>>>(qdh, kdh, vt, out, attn);
}

// Round 12
// 51.497 us; speedup vs baseline: 1.2944x; 1.2944x over previous
//
#include <hip/hip_runtime.h>
#include <hip/hip_fp16.h>
#include <math.h>

#define NQ 8
#define DK 64
#define NB 8
#define NS 1024
#define RB 4            // rows per block in attn kernel
#define EPITCH 1032     // padded halfs per e16 row

typedef _Float16 h2v __attribute__((ext_vector_type(2)));

__device__ __forceinline__ float fdot2h(unsigned qu, unsigned ku, float acc) {
#if defined(__has_builtin) && __has_builtin(__builtin_amdgcn_fdot2)
    union { unsigned u; h2v h; } a, b;
    a.u = qu; b.u = ku;
    return __builtin_amdgcn_fdot2(a.h, b.h, acc, false);
#else
    __half2 qh = *(__half2*)&qu, kh = *(__half2*)&ku;
    float2 qf = __half22float2(qh), kf = __half22float2(kh);
    return fmaf(qf.x, kf.x, fmaf(qf.y, kf.y, acc));
#endif
}

// ---------------- prep: V2 fp16 GEMM (blocks 0..2047) + density features ----------------
// qdh/kdh fp16 [tok][n*4 + {d0,d1,re,im}]; factor 2 folded into kdh cross terms.
// v2 fp16 pair-interleaved: [b][pair=t/2][d][t&1]  (128 halfs = 256 B per pair-row)
__global__ __launch_bounds__(256) void prep_kernel(
    const float* __restrict__ x,
    const float* __restrict__ theta_q,
    const float* __restrict__ theta_k,
    const float* __restrict__ Wv,
    const float* __restrict__ bv,
    __half* __restrict__ qdh, __half* __restrict__ kdh,
    __half* __restrict__ v2) {
    int bid = blockIdx.x;
    int tid = threadIdx.x;
    if (bid < 2048) {
        // values = x @ Wv^T + bv (4 partial chains), stored fp16 pair-interleaved
        int t = bid * 4 + (tid >> 6);
        int d = tid & 63;
        const float4* xr = (const float4*)(x + (size_t)t * DK);
        const float4* wr = (const float4*)(Wv + (size_t)d * DK);
        float a0 = bv[d], a1 = 0.f, a2 = 0.f, a3 = 0.f;
#pragma unroll
        for (int j = 0; j < DK / 4; ++j) {
            float4 xv = xr[j], wv = wr[j];
            a0 = fmaf(xv.x, wv.x, a0);
            a1 = fmaf(xv.y, wv.y, a1);
            a2 = fmaf(xv.z, wv.z, a2);
            a3 = fmaf(xv.w, wv.w, a3);
        }
        float v = (a0 + a1) + (a2 + a3);
        int b = t >> 10, ti = t & 1023;
        v2[((size_t)(b * 512 + (ti >> 1)) * 64 + d) * 2 + (ti & 1)] = __float2half_rn(v);
    } else {
        // per-(side,qubit) theta trig table, computed once per block
        __shared__ float tt[2][NQ][6];   // ct,st,cmpo,smpo,cpmo,spmo
        if (tid < 16) {
            int side = tid >> 3, n = tid & 7;
            const float* thp = side ? theta_k : theta_q;
            float phi = thp[n * 3 + 0], th = thp[n * 3 + 1], om = thp[n * 3 + 2];
            float st, ct; __sincosf(0.5f * th, &st, &ct);
            float smpo, cmpo; __sincosf(0.5f * (phi + om), &smpo, &cmpo);
            float spmo, cpmo; __sincosf(0.5f * (phi - om), &spmo, &cpmo);
            tt[side][n][0] = ct;  tt[side][n][1] = st;
            tt[side][n][2] = cmpo; tt[side][n][3] = smpo;
            tt[side][n][4] = cpmo; tt[side][n][5] = spmo;
        }
        __syncthreads();

        int gid = (bid - 2048) * 256 + tid;   // 0..65535
        int tok = gid >> 3;
        int n = gid & 7;
        float xin = x[(size_t)tok * DK + n];
        float ex = __expf(2.0f * xin);               // fast tanh
        float xn = 1.0f - 2.0f / (ex + 1.0f);
        float s, c;
        __sincosf(xn * 1.57079632679489662f, &s, &c);

#pragma unroll
        for (int side = 0; side < 2; ++side) {
            float ct = tt[side][n][0], st = tt[side][n][1];
            float cmpo = tt[side][n][2], smpo = tt[side][n][3];
            float cpmo = tt[side][n][4], spmo = tt[side][n][5];
            float a = ct * c, b2 = st * s, cc = st * c, d2 = ct * s;
            float a0re =  cmpo * a - cpmo * b2;
            float a0im = -smpo * a - spmo * b2;
            float a1re =  cpmo * cc + cmpo * d2;
            float a1im = -spmo * cc + smpo * d2;
            float d0 = fmaf(a0re, a0re, a0im * a0im);
            float d1 = fmaf(a1re, a1re, a1im * a1im);
            float ur = fmaf(a1re, a0re, a1im * a0im);
            float ui = fmaf(a1im, a0re, -a1re * a0im);
            if (side == 0) {
                __half2* qp = (__half2*)(qdh + (size_t)tok * 32 + n * 4);
                qp[0] = __floats2half2_rn(d0, d1);
                qp[1] = __floats2half2_rn(ur, ui);
            } else {
                __half2* kp = (__half2*)(kdh + (size_t)tok * 32 + n * 4);
                kp[0] = __floats2half2_rn(d0, d1);
                kp[1] = __floats2half2_rn(2.f * ur, 2.f * ui);
            }
        }
    }
}

// ---------------- attn: fused scores -> softmax -> attn + dot2 PV ----------------
// 2048 blocks x 256 threads (4 waves); block owns 4 rows of one batch.
// Phase 1: wave w owns tokens [256w,256w+256), j-outer (16 K-regs live), all 4 rows.
// Phase 3: PV via v_dot2_f32_f16 on pair-interleaved fp16 V (coalesced 16B/lane).
__global__ __launch_bounds__(256, 4) void attn_kernel(
    const __half* __restrict__ qdh, const __half* __restrict__ kdh,
    const __half* __restrict__ v2,
    float* __restrict__ out, float* __restrict__ attn) {
    __shared__ __align__(16) unsigned char smem[16 * RB * 64 * 4];  // 16 KB
    __half (*e16)[EPITCH] = (__half(*)[EPITCH])smem;                // 8.3 KB used
    float* red = (float*)smem;                                      // aliased after PV
    __shared__ float red_lds[4][RB];
    __shared__ float inv_lds[RB];

    int tid = threadIdx.x;
    int gr0 = blockIdx.x * RB;            // global row base (= b*NS + s0)
    int b = gr0 >> 10;
    int w = tid >> 6, lane = tid & 63;

    const __half* kfb = kdh + (size_t)b * NS * 32;

    // q density features for the 4 rows -> SGPRs (wave-uniform)
    unsigned sq[RB][16];
#pragma unroll
    for (int r = 0; r < RB; ++r) {
        const unsigned* qp = (const unsigned*)(qdh + (size_t)(gr0 + r) * 32);
#pragma unroll
        for (int i = 0; i < 16; ++i) sq[r][i] = __builtin_amdgcn_readfirstlane(qp[i]);
    }

    // ---- Phase 1: scores + exp; wave's 256-token slice, j-outer ----
    float sums[RB];
#pragma unroll
    for (int r = 0; r < RB; ++r) sums[r] = 0.f;

    int t0 = w * 256;
#pragma unroll
    for (int j = 0; j < 4; ++j) {
        int t = t0 + j * 64 + lane;
        const uint4* kp = (const uint4*)(kfb + (size_t)t * 32);
        uint4 k0 = kp[0], k1 = kp[1], k2 = kp[2], k3 = kp[3];
#pragma unroll
        for (int r = 0; r < RB; ++r) {
            float m0 = fdot2h(sq[r][ 0], k0.x, fdot2h(sq[r][ 1], k0.y, 0.f));
            float m1 = fdot2h(sq[r][ 2], k0.z, fdot2h(sq[r][ 3], k0.w, 0.f));
            float m2 = fdot2h(sq[r][ 4], k1.x, fdot2h(sq[r][ 5], k1.y, 0.f));
            float m3 = fdot2h(sq[r][ 6], k1.z, fdot2h(sq[r][ 7], k1.w, 0.f));
            float m4 = fdot2h(sq[r][ 8], k2.x, fdot2h(sq[r][ 9], k2.y, 0.f));
            float m5 = fdot2h(sq[r][10], k2.z, fdot2h(sq[r][11], k2.w, 0.f));
            float m6 = fdot2h(sq[r][12], k3.x, fdot2h(sq[r][13], k3.y, 0.f));
            float m7 = fdot2h(sq[r][14], k3.z, fdot2h(sq[r][15], k3.w, 0.f));
            float core = ((m0 * m1) * (m2 * m3)) * ((m4 * m5) * (m6 * m7));
            float e = __expf(fmaf(core, 0.5f, 0.5f));   // score in [0.5,1] -> no max
            e16[r][t] = __float2half_rn(e);
            sums[r] += e;
        }
    }

    // per-wave partial row sums -> cross-wave combine
#pragma unroll
    for (int r = 0; r < RB; ++r) {
#pragma unroll
        for (int m = 1; m < 64; m <<= 1) sums[r] += __shfl_xor(sums[r], m, 64);
    }
    if (lane == 0) {
#pragma unroll
        for (int r = 0; r < RB; ++r) red_lds[w][r] = sums[r];
    }
    __syncthreads();
    if (tid < RB)
        inv_lds[tid] = 1.f / (red_lds[0][tid] + red_lds[1][tid] + red_lds[2][tid] + red_lds[3][tid]);
    __syncthreads();

    // ---- Phase 2: write normalized attn (coalesced float4) ----
    float* ab = attn + (size_t)gr0 * NS;
#pragma unroll
    for (int r = 0; r < RB; ++r) {
        float iv = inv_lds[r];
        uint2 raw = *(const uint2*)&e16[r][tid * 4];
        __half2* hp = (__half2*)&raw;
        float2 lo = __half22float2(hp[0]), hi = __half22float2(hp[1]);
        *(float4*)&ab[(size_t)r * NS + tid * 4] =
            make_float4(lo.x * iv, lo.y * iv, hi.x * iv, hi.y * iv);
    }

    // ---- Phase 3: PV via dot2. thread (tg 0..15, dg 0..15); pair p = jj*16+tg ----
    int tg = tid >> 4, dg = tid & 15;
    const __half* v2b = v2 + (size_t)b * 512 * 128;
    float acc[RB][4];
#pragma unroll
    for (int r = 0; r < RB; ++r) { acc[r][0] = acc[r][1] = acc[r][2] = acc[r][3] = 0.f; }

    for (int jj = 0; jj < 32; ++jj) {
        int p = jj * 16 + tg;                         // token pair index 0..511
        uint4 vv = *(const uint4*)(v2b + (size_t)p * 128 + dg * 8);  // 4 dims x half2
        unsigned ep[RB];
#pragma unroll
        for (int r = 0; r < RB; ++r) ep[r] = *(const unsigned*)&e16[r][2 * p];
#pragma unroll
        for (int r = 0; r < RB; ++r) {
            acc[r][0] = fdot2h(ep[r], vv.x, acc[r][0]);
            acc[r][1] = fdot2h(ep[r], vv.y, acc[r][1]);
            acc[r][2] = fdot2h(ep[r], vv.z, acc[r][2]);
            acc[r][3] = fdot2h(ep[r], vv.w, acc[r][3]);
        }
    }

    // ---- out reduce: alias e16 buffer as [16 tg][RB][64] fp32 scratch ----
    __syncthreads();                     // all PV reads of e16 complete
#pragma unroll
    for (int r = 0; r < RB; ++r) {
        *(float4*)&red[((size_t)tg * RB + r) * 64 + dg * 4] =
            make_float4(acc[r][0], acc[r][1], acc[r][2], acc[r][3]);
    }
    __syncthreads();
    {
        int r2 = tid >> 6, d = tid & 63;
        float o = 0.f;
#pragma unroll
        for (int g = 0; g < 16; ++g) o += red[((size_t)g * RB + r2) * 64 + d];
        out[((size_t)(gr0 + r2)) * DK + d] = o * inv_lds[r2];
    }
}

extern "C" void kernel_launch(void* const* d_in, const int* in_sizes, int n_in,
                              void* d_out, int out_size, void* d_ws, size_t ws_size,
                              hipStream_t stream) {
    const float* x       = (const float*)d_in[0];
    const float* theta_q = (const float*)d_in[1];
    const float* theta_k = (const float*)d_in[2];
    const float* W_v     = (const float*)d_in[3];
    const float* b_v     = (const float*)d_in[4];

    float* out  = (float*)d_out;                        // [8,1024,64]
    float* attn = (float*)d_out + (size_t)NB * NS * DK; // [8,1024,1024]

    __half* qdh = (__half*)d_ws;                         // 512 KB fp16
    __half* kdh = qdh + (size_t)NB * NS * 32;            // 512 KB fp16
    __half* v2  = kdh + (size_t)NB * NS * 32;            // 1 MB fp16 (pair-interleaved V)

    prep_kernel<<<2048 + NB * NS * NQ / 256, 256, 0, stream>>>(
        x, theta_q, theta_k, W_v, b_v, qdh, kdh, v2);
    attn_kernel<<<NB * NS / RB, 256, 0, stream>>>(qdh, kdh, v2, out, attn);
}